// Round 20
// baseline (17762.872 us; speedup 1.0000x reference)
//
#include <hip/hip_runtime.h>
#include <hip/hip_bf16.h>
#include <math.h>

// Problem constants (fixed by the reference)
#define NV 20000
#define NH 512
#define NT 1024
#define NB 32
#define MAXD 64

// Recurrent-phase geometry (R20): h-half only (K=512), 128 blocks,
// 16-block sync domains.
#define NGRP 8      // groups (independent batch-row sets)
#define BPG 16      // blocks per group  (was 32)
#define BPB 4       // batch rows per group
#define UPB 32      // hidden units per block (was 16)
#define ROWS 128    // gate rows per block = 4*UPB
#define NTH 512
#define KSN 16      // k-slices per block
#define KPT 32      // k elements per slice

typedef int v4i __attribute__((ext_vector_type(4)));

// ws layout:
//   path_bf: NV*NH bf16   = 20.48 MB
//   ztab   : NV*4NH bf16  = 81.92 MB   (ZTAB[v][j] = Wx.path[v] + b, j<2048)
//   hbuf   : 2*NB*NH f32  = 131 KB     (parity-double-buffered h exchange)
//   prog   : 256 ints                  (2 words per producer block)
// total ~= 102.5 MB  (< 108 MB proven available in R19)

__global__ void init_kernel(int* __restrict__ prog) {
  int i = blockIdx.x * blockDim.x + threadIdx.x;
  if (i < 256)
    __hip_atomic_store(&prog[i], 0, __ATOMIC_RELAXED, __HIP_MEMORY_SCOPE_SYSTEM);
}

// One block per node; writes bf16 (feeds only ZTAB; bf16 error ~1e-4 on z).
__global__ __launch_bounds__(256)
void path_kernel(const int* __restrict__ parents,
                 const float* __restrict__ weight,
                 const float* __restrict__ emb,
                 __hip_bfloat16* __restrict__ path_bf) {
  int v = blockIdx.x;
  int h = threadIdx.x;
  float acc0 = 0.f, acc1 = 0.f;
  float w = 1.f;
  int cur = v;
#pragma unroll 1
  for (int d = 0; d < MAXD; ++d) {
    if (cur < 0) break;
    const float* row = emb + (size_t)cur * NH;
    acc0 = fmaf(w, row[h], acc0);
    acc1 = fmaf(w, row[h + 256], acc1);
    w *= weight[cur];
    cur = parents[cur];
  }
  path_bf[(size_t)v * NH + h] = __float2bfloat16(acc0);
  path_bf[(size_t)v * NH + h + 256] = __float2bfloat16(acc1);
}

// f(k) = k + k/32 : +1 dword pad per 32 -> conflict-free LDS columns
__device__ __forceinline__ int fpad(int k) { return k + (k >> 5); }

// Phase A: ZTAB[v][j] = sum_k Wx[j][k]*path[v][k] + b[j].  Fully parallel:
// 256 blocks = 32 j-chunks (64 rows) x 8 v-slices (2500 v each, 4/iter).
// Register-resident Wx slice (64 f/thread), R13-style tile.
__global__ __launch_bounds__(NTH, 1)
void ztab_kernel(const __hip_bfloat16* __restrict__ path_bf,
                 const float* __restrict__ gate_w,
                 const float* __restrict__ gate_b,
                 __hip_bfloat16* __restrict__ ztab) {
  __shared__ float in_s[4][NH + NH / 32];
  __shared__ float p_s[KSN][64 * 4 + 1];

  const int bid = blockIdx.x;
  const int jblk = bid & 31;   // rows [jblk*64, +64)
  const int vsl = bid >> 5;    // v in [vsl*2500, +2500)
  const int tid = threadIdx.x;
  const int jg = tid >> 4;     // 0..31 -> 2 rows each
  const int ks = tid & 15;     // 0..15 -> 32 k each

  float w[2][KPT];
#pragma unroll
  for (int jj = 0; jj < 2; ++jj) {
    int j = jblk * 64 + jg * 2 + jj;
    const float* wr = gate_w + (size_t)j * (2 * NH) + ks * KPT;  // x half
#pragma unroll
    for (int kk = 0; kk < KPT; ++kk) w[jj][kk] = wr[kk];
  }

  const int sb2 = tid >> 7;
  const int off4 = (tid & 127) * 4;

#pragma unroll 1
  for (int it = 0; it < 625; ++it) {
    int v0 = vsl * 2500 + it * 4;
    {
      const __hip_bfloat16* src = path_bf + (size_t)(v0 + sb2) * NH + off4;
      float* dst = &in_s[sb2][fpad(off4)];
      dst[0] = __bfloat162float(src[0]);
      dst[1] = __bfloat162float(src[1]);
      dst[2] = __bfloat162float(src[2]);
      dst[3] = __bfloat162float(src[3]);
    }
    __syncthreads();

    float acc[2][4];
#pragma unroll
    for (int jj = 0; jj < 2; ++jj)
#pragma unroll
      for (int bi = 0; bi < 4; ++bi) acc[jj][bi] = 0.f;
    const int fb = fpad(ks * KPT);
#pragma unroll
    for (int bi = 0; bi < 4; ++bi) {
      const float* inp = &in_s[bi][fb];
#pragma unroll
      for (int kk = 0; kk < KPT; ++kk) {
        float x = inp[kk];
        acc[0][bi] = fmaf(w[0][kk], x, acc[0][bi]);
        acc[1][bi] = fmaf(w[1][kk], x, acc[1][bi]);
      }
    }
#pragma unroll
    for (int jj = 0; jj < 2; ++jj) {
      int r64 = jg * 2 + jj;
#pragma unroll
      for (int bi = 0; bi < 4; ++bi)
        p_s[ks][r64 * 4 + bi] = acc[jj][bi];
    }
    __syncthreads();

    if (tid < 256) {
      int r64 = tid >> 2, bi = tid & 3;
      float s = 0.f;
#pragma unroll
      for (int k2 = 0; k2 < KSN; ++k2) s += p_s[k2][tid];
      s += gate_b[jblk * 64 + r64];
      ztab[(size_t)(v0 + bi) * (4 * NH) + jblk * 64 + r64] = __float2bfloat16(s);
    }
    __syncthreads();
  }
}

// Recurrent phase: 128 blocks = 8 groups x 16 blocks; block owns 32 units
// (128 gate rows) x K=512 (h half only; x half comes from ZTAB via zx_s
// prefetch). Exchange machinery identical to R13 (proven): parity hbuf,
// bypass stores, wave-level vmcnt drain -> per-producer prog word (2 per
// block: gate threads span 2 waves), 8-lane dwordx4 poll over the group's
// 32 words, 128-lane fused 64B staging loads.
__global__ __launch_bounds__(NTH, 1)
void lstm_kernel(const int* __restrict__ ev,
                 const __hip_bfloat16* __restrict__ ztab,
                 const float* __restrict__ gate_w,
                 float* __restrict__ hbuf,   // [2][NB][NH]
                 int* __restrict__ prog,     // [NGRP][BPG][2]
                 float* __restrict__ out) {  // [3][NT][NB][NH]
  __shared__ float h_s[BPB][NH + NH / 32];
  __shared__ float p_s[KSN][ROWS * BPB + 1];   // [16][513]
  __shared__ float zx_s[2][BPB][ROWS];
  __shared__ float zred[ROWS * BPB];           // 512
  __shared__ float c_s[BPB][UPB];

  const int bid = blockIdx.x;
  const int grp = bid >> 4;
  const int blk = bid & 15;
  const int b0 = grp * BPB;
  const int u0 = blk * UPB;
  const int tid = threadIdx.x;
  const int jg = tid >> 4;   // 0..31: 4-row group
  const int ks = tid & 15;   // 0..15: 32-k slice

  // Wh slice: w[jj][kk] = gate_w[j][512 + ks*32 + kk], j = g*NH + u0 + uu
  float w[4][KPT];
#pragma unroll
  for (int jj = 0; jj < 4; ++jj) {
    int r = jg * 4 + jj;                          // 0..127
    int j = (r >> 5) * NH + u0 + (r & 31);
    const float* wr = gate_w + (size_t)j * (2 * NH) + NH + ks * KPT;
#pragma unroll
    for (int kk = 0; kk < KPT; ++kk) w[jj][kk] = wr[kk];
  }

  if (tid < BPB * UPB) c_s[tid >> 5][tid & 31] = 0.f;

  const int hrow = tid >> 5;         // h-stage (tid<128): batch row
  const int hc16 = (tid & 31) * 16;  // h-stage: 16-float (64B) chunk
  const size_t plane = (size_t)NT * NB * NH;
  const int* pollp4 = prog + grp * 32 + (tid & 7) * 4;

  // preload zx(0)
  {
    int bi = tid >> 7, idx = tid & 127;
    int e = ev[0 * NB + b0 + bi];
    int j = (idx >> 5) * NH + u0 + (idx & 31);
    zx_s[0][bi][idx] = __bfloat162float(ztab[(size_t)e * (4 * NH) + j]);
  }

#pragma unroll 1
  for (int t = 0; t < NT; ++t) {
    const bool more = (t + 1 < NT);

    // ---- wait for group's h(t) producers: 8 lanes x dwordx4 ----
    if (t > 0 && tid < 8) {
      v4i pv;
      for (;;) {
        asm volatile("global_load_dwordx4 %0, %1, off sc0 sc1\n\ts_waitcnt vmcnt(0)"
                     : "=v"(pv) : "v"(pollp4) : "memory");
        bool ok = (pv[0] >= t) && (pv[1] >= t) && (pv[2] >= t) && (pv[3] >= t);
        if ((__ballot(ok) & 0xFFull) == 0xFFull) break;
        __builtin_amdgcn_s_sleep(1);
      }
    }
    __syncthreads();   // A0

    // ---- stage h(t): 128 lanes x one 64B line (4 fused dwordx4) ----
    if (tid < 128) {
      float* d = &h_s[hrow][fpad(hc16)];
      if (t > 0) {
        const float* hsrc =
            hbuf + ((size_t)(t & 1) * NB + (b0 + hrow)) * NH + hc16;
        float4 ha, hb, hc, hd;
        asm volatile(
            "global_load_dwordx4 %0, %4, off sc0 sc1\n\t"
            "global_load_dwordx4 %1, %4, off offset:16 sc0 sc1\n\t"
            "global_load_dwordx4 %2, %4, off offset:32 sc0 sc1\n\t"
            "global_load_dwordx4 %3, %4, off offset:48 sc0 sc1\n\t"
            "s_waitcnt vmcnt(0)"
            : "=&v"(ha), "=&v"(hb), "=&v"(hc), "=&v"(hd)
            : "v"(hsrc)
            : "memory");
        *(float4*)(d + 0) = ha;
        *(float4*)(d + 4) = hb;
        *(float4*)(d + 8) = hc;
        *(float4*)(d + 12) = hd;
      } else {
#pragma unroll
        for (int q = 0; q < 16; ++q) d[q] = 0.f;
      }
    }
    __syncthreads();   // A1: h(t) staged

    // ---- h-half GEMM: K=512, per thread 4 rows x 4 batch x 32 k ----
    float acc[4][BPB];
#pragma unroll
    for (int jj = 0; jj < 4; ++jj)
#pragma unroll
      for (int bi = 0; bi < BPB; ++bi) acc[jj][bi] = 0.f;
    {
      const int fb = fpad(ks * KPT);
#pragma unroll
      for (int bi = 0; bi < BPB; ++bi) {
        const float* inp = &h_s[bi][fb];
#pragma unroll
        for (int kk = 0; kk < KPT; ++kk) {
          float x = inp[kk];
          acc[0][bi] = fmaf(w[0][kk], x, acc[0][bi]);
          acc[1][bi] = fmaf(w[1][kk], x, acc[1][bi]);
          acc[2][bi] = fmaf(w[2][kk], x, acc[2][bi]);
          acc[3][bi] = fmaf(w[3][kk], x, acc[3][bi]);
        }
      }
    }
#pragma unroll
    for (int jj = 0; jj < 4; ++jj) {
      int r = jg * 4 + jj;
#pragma unroll
      for (int bi = 0; bi < BPB; ++bi)
        p_s[ks][r * BPB + bi] = acc[jj][bi];
    }
    __syncthreads();   // B: p_s complete; h_s dead

    // ---- prefetch zx(t+1) (cached ZTAB gather; off critical path) ----
    if (more) {
      int bi = tid >> 7, idx = tid & 127;
      int e = ev[(t + 1) * NB + b0 + bi];
      int j = (idx >> 5) * NH + u0 + (idx & 31);
      zx_s[(t + 1) & 1][bi][idx] = __bfloat162float(ztab[(size_t)e * (4 * NH) + j]);
    }

    // ---- reduce 16 k-slices + zx ----
    {
      float s = 0.f;
#pragma unroll
      for (int k2 = 0; k2 < KSN; ++k2) s += p_s[k2][tid];
      s += zx_s[t & 1][tid & 3][tid >> 2];
      zred[tid] = s;
    }
    __syncthreads();   // C: zred complete

    // ---- gates + state update + handoff (128 threads = waves 0,1) ----
    if (tid < BPB * UPB) {
      int bi = tid >> 5, uu = tid & 31;
      float zi = zred[(0 * UPB + uu) * BPB + bi];
      float zf = zred[(1 * UPB + uu) * BPB + bi];
      float zg = zred[(2 * UPB + uu) * BPB + bi];
      float zo = zred[(3 * UPB + uu) * BPB + bi];
      float ig = 1.f / (1.f + expf(-zi));
      float fg = 1.f / (1.f + expf(-zf));
      float gg = tanhf(zg);
      float ogv = 1.f / (1.f + expf(-zo));
      float cv = fmaf(fg, c_s[bi][uu], ig * gg);
      float hvv = ogv * tanhf(cv);
      c_s[bi][uu] = cv;
      int b = b0 + bi, u = u0 + uu;
      if (more) {
        float* hdst = hbuf + ((size_t)((t + 1) & 1) * NB + b) * NH + u;
        __hip_atomic_store(hdst, hvv, __ATOMIC_RELAXED, __HIP_MEMORY_SCOPE_SYSTEM);
      }
      // per-wave drain + signal (gate threads span waves 0 and 1)
      if (more && ((tid & 63) == 0)) {
        asm volatile("s_waitcnt vmcnt(0)" ::: "memory");
        int nv = t + 1;
        int* myprog = prog + grp * 32 + blk * 2 + (tid >> 6);
        asm volatile("global_store_dword %0, %1, off sc0 sc1"
                     :: "v"(myprog), "v"(nv) : "memory");
      }
      size_t o0 = ((size_t)t * NB + b) * NH + u;
      out[o0] = hvv;
      out[plane + o0] = cv;
      out[2 * plane + o0] = ogv;
    }
    // no end-of-step barrier: next poll + A0 covers it
  }
}

extern "C" void kernel_launch(void* const* d_in, const int* in_sizes, int n_in,
                              void* d_out, int out_size, void* d_ws, size_t ws_size,
                              hipStream_t stream) {
  const int* ev = (const int*)d_in[0];
  const int* parents = (const int*)d_in[1];
  const float* weight = (const float*)d_in[2];
  const float* emb = (const float*)d_in[3];
  const float* gate_w = (const float*)d_in[4];
  const float* gate_b = (const float*)d_in[5];
  float* out = (float*)d_out;

  char* ws = (char*)d_ws;
  __hip_bfloat16* path_bf = (__hip_bfloat16*)ws;
  size_t path_bytes = (size_t)NV * NH * sizeof(__hip_bfloat16);        // 20.48MB
  __hip_bfloat16* ztab = (__hip_bfloat16*)(ws + path_bytes);
  size_t ztab_bytes = (size_t)NV * 4 * NH * sizeof(__hip_bfloat16);    // 81.92MB
  float* hbuf = (float*)(ws + path_bytes + ztab_bytes);
  size_t hbuf_bytes = (size_t)2 * NB * NH * sizeof(float);             // 131KB
  int* prog = (int*)(ws + path_bytes + ztab_bytes + hbuf_bytes);

  init_kernel<<<1, 256, 0, stream>>>(prog);
  path_kernel<<<NV, 256, 0, stream>>>(parents, weight, emb, path_bf);
  ztab_kernel<<<256, NTH, 0, stream>>>(path_bf, gate_w, gate_b, ztab);
  lstm_kernel<<<NGRP * BPG, NTH, 0, stream>>>(ev, ztab, gate_w, hbuf, prog, out);
}

// Round 22
// 13205.724 us; speedup vs baseline: 1.3451x; 1.3451x over previous
//
#include <hip/hip_runtime.h>
#include <math.h>

// Problem constants (fixed by the reference)
#define NV 20000
#define NH 512
#define NT 1024
#define NB 32
#define MAXD 64

// LSTM persistent-kernel geometry (R13-proven chassis)
#define NGRP 8      // groups (independent batch-row sets); sync domain = 1 group
#define BPG 32      // blocks per group
#define BPB 4       // batch rows per group  (NB / NGRP)
#define UPB 16      // hidden units per block (NH / BPG)
#define NJ 64       // gate rows per block = 4*UPB
#define KTOT 1024   // 2*NH
#define NTH 512
#define KHALF 16    // k elements per thread per half (x-half + h-half = 32)

typedef int v4i __attribute__((ext_vector_type(4)));
typedef int v2i __attribute__((ext_vector_type(2)));

// ws layout: [ path: NV*NH f32 | hpair: 2*NB*NH*(val,tag) = 512KB |
//              prog: 256 ints ] ~= 41.5 MB

__global__ void init_kernel(int* __restrict__ hpair, int* __restrict__ prog) {
  int i = blockIdx.x * blockDim.x + threadIdx.x;
  if (i < 2 * NB * NH * 2)
    __hip_atomic_store(&hpair[i], 0, __ATOMIC_RELAXED, __HIP_MEMORY_SCOPE_SYSTEM);
  if (i < 256)
    __hip_atomic_store(&prog[i], 0, __ATOMIC_RELAXED, __HIP_MEMORY_SCOPE_SYSTEM);
}

// One block per node: all 256 threads walk the same parent chain (uniform),
// each thread accumulates 2 of the 512 embedding columns (coalesced).
__global__ __launch_bounds__(256)
void path_kernel(const int* __restrict__ parents,
                 const float* __restrict__ weight,
                 const float* __restrict__ emb,
                 float* __restrict__ path) {
  int v = blockIdx.x;
  int h = threadIdx.x;
  float acc0 = 0.f, acc1 = 0.f;
  float w = 1.f;
  int cur = v;
#pragma unroll 1
  for (int d = 0; d < MAXD; ++d) {
    if (cur < 0) break;
    const float* row = emb + (size_t)cur * NH;
    acc0 = fmaf(w, row[h], acc0);
    acc1 = fmaf(w, row[h + 256], acc1);
    w *= weight[cur];
    cur = parents[cur];
  }
  path[(size_t)v * NH + h] = acc0;
  path[(size_t)v * NH + h + 256] = acc1;
}

// f(k) = k + k/32 : +1 dword pad per 32 -> conflict-free LDS columns
__device__ __forceinline__ int fpad(int k) { return k + (k >> 5); }

// Persistent LSTM, R22: EARLY SIGNAL (no producer drain) + TAG-VERIFIED h.
// h moves as 8B {f32 val, int32 tag=t+1} pairs (dwordx2 stores, atomic unit).
// Producer fires the prog signal IMMEDIATELY after its pair stores are
// issued -- the vmcnt(0) drain (a full CP round trip on the serial chain in
// R13..R19) is deleted. The signal is only a HINT; consumers keep R13's
// cheap 8-lane prog poll as a gate (spin pressure stays at the proven-OK
// level -- R16/R18's regression was 128-256 lanes polling data), then do
// the staging load ONCE with embedded-tag verification (R16's fused
// 8xdwordx4 pattern, proven correct); rare micro-retries absorb the
// signal-leads-data race. Tags are the truth. Two-phase overwrite-safety
// carries over from R13: a producer reaches step s+2's stores only after
// every peer consumed step s+1. t=0 stages zeros directly (no loads);
// parity buffers end each run holding tag 1023 at every address, so stale
// accepts are impossible across graph replays (init re-zeroes anyway).
__global__ __launch_bounds__(NTH, 1)
void lstm_kernel(const int* __restrict__ ev,
                 const float* __restrict__ path,
                 const float* __restrict__ gate_w,
                 const float* __restrict__ gate_b,
                 int* __restrict__ hpair,    // [2][NB][NH][2] {val,tag}
                 int* __restrict__ prog,     // [NGRP][BPG] per-producer hint
                 float* __restrict__ out) {  // [3][NT][NB][NH]
  __shared__ float in_s[BPB][KTOT + KTOT / 32];   // [x(t) | h(t)] padded
  __shared__ float p_s[32][NJ * BPB + 1];         // stride 257 -> conflict-free
  __shared__ float zred[NJ * BPB];
  __shared__ float c_s[BPB][UPB];

  const int bid = blockIdx.x;
  const int grp = bid >> 5;   // group = consecutive 32-block range
  const int blk = bid & 31;
  const int b0 = grp * BPB;
  const int u0 = blk * UPB;
  const int tid = threadIdx.x;
  const int jg = tid >> 5;   // 0..15: which 4-row group of gate rows
  const int ks = tid & 31;   // 0..31: which k-slice (16 x-k + 16 h-k)

  // gate_w slice:
  // w[jj][0..15]  = W[j][ks*16 .. +16)          (x half)
  // w[jj][16..31] = W[j][512 + ks*16 .. +16)    (h half)
  float w[4][2 * KHALF];
#pragma unroll
  for (int jj = 0; jj < 4; ++jj) {
    int r = jg * 4 + jj;                        // 0..63: gate*16 + uu
    int j = (r >> 4) * NH + u0 + (r & 15);      // global gate row
    const float* wx = gate_w + (size_t)j * KTOT + ks * KHALF;
    const float* wh = gate_w + (size_t)j * KTOT + NH + ks * KHALF;
#pragma unroll
    for (int kk = 0; kk < KHALF; ++kk) {
      w[jj][kk] = wx[kk];
      w[jj][KHALF + kk] = wh[kk];
    }
  }

  if (tid < BPB * UPB) c_s[tid >> 4][tid & 15] = 0.f;

  // staging maps
  const int sb2 = tid >> 7;          // x-prefetch: row 0..3
  const int off4 = (tid & 127) * 4;  // x-prefetch: 4-float chunk
  const int hrow = tid >> 5;         // h-stage (tid<128): row 0..3
  const int hc16 = (tid & 31) * 16;  // h-stage: 16 units (128B of pairs)
  const size_t plane = (size_t)NT * NB * NH;
  int* myprog = prog + grp * BPG + blk;
  const int* pollp4 = prog + grp * BPG + (tid & 7) * 4;

  // pre-stage x(0) (cached loads; visibility via barrier A1 at t=0)
  {
    int e = ev[0 * NB + b0 + sb2];
    float4 v0 = *(const float4*)(path + (size_t)e * NH + off4);
    *(float4*)&in_s[sb2][fpad(off4)] = v0;
  }

#pragma unroll 1
  for (int t = 0; t < NT; ++t) {
    const bool more = (t + 1 < NT);

    // ---- gate: wait for group's h(t) producer hints (8 lanes x dwordx4) --
    if (t > 0 && tid < 8) {
      v4i pv;
      for (;;) {
        asm volatile("global_load_dwordx4 %0, %1, off sc0 sc1\n\ts_waitcnt vmcnt(0)"
                     : "=v"(pv) : "v"(pollp4) : "memory");
        bool ok = (pv[0] >= t) && (pv[1] >= t) && (pv[2] >= t) && (pv[3] >= t);
        if ((__ballot(ok) & 0xFFull) == 0xFFull) break;
        __builtin_amdgcn_s_sleep(1);
      }
    }
    __syncthreads();   // A0: hint passed; prev step's LDS reads all complete

    // ---- stage h(t): 128 lanes x 16 pairs (128B), tag-verified ----
    if (tid < 128) {
      float* d = &in_s[hrow][fpad(NH + hc16)];  // 16-chunk: pad-affine
      if (t > 0) {
        const int* hsrc =
            hpair + (((size_t)(t & 1) * NB + (b0 + hrow)) * NH + hc16) * 2;
        v4i p0, p1, p2, p3, p4, p5, p6, p7;
        for (;;) {
          asm volatile(
              "global_load_dwordx4 %0, %8, off sc0 sc1\n\t"
              "global_load_dwordx4 %1, %8, off offset:16 sc0 sc1\n\t"
              "global_load_dwordx4 %2, %8, off offset:32 sc0 sc1\n\t"
              "global_load_dwordx4 %3, %8, off offset:48 sc0 sc1\n\t"
              "global_load_dwordx4 %4, %8, off offset:64 sc0 sc1\n\t"
              "global_load_dwordx4 %5, %8, off offset:80 sc0 sc1\n\t"
              "global_load_dwordx4 %6, %8, off offset:96 sc0 sc1\n\t"
              "global_load_dwordx4 %7, %8, off offset:112 sc0 sc1\n\t"
              "s_waitcnt vmcnt(0)"
              : "=&v"(p0), "=&v"(p1), "=&v"(p2), "=&v"(p3),
                "=&v"(p4), "=&v"(p5), "=&v"(p6), "=&v"(p7)
              : "v"(hsrc)
              : "memory");
          bool ok = (p0[1] == t) & (p0[3] == t) & (p1[1] == t) & (p1[3] == t) &
                    (p2[1] == t) & (p2[3] == t) & (p3[1] == t) & (p3[3] == t) &
                    (p4[1] == t) & (p4[3] == t) & (p5[1] == t) & (p5[3] == t) &
                    (p6[1] == t) & (p6[3] == t) & (p7[1] == t) & (p7[3] == t);
          if (ok) break;   // usually first try: hint already gated arrival
          __builtin_amdgcn_s_sleep(1);
        }
        float4 q0, q1, q2, q3;
        q0.x = __int_as_float(p0[0]); q0.y = __int_as_float(p0[2]);
        q0.z = __int_as_float(p1[0]); q0.w = __int_as_float(p1[2]);
        q1.x = __int_as_float(p2[0]); q1.y = __int_as_float(p2[2]);
        q1.z = __int_as_float(p3[0]); q1.w = __int_as_float(p3[2]);
        q2.x = __int_as_float(p4[0]); q2.y = __int_as_float(p4[2]);
        q2.z = __int_as_float(p5[0]); q2.w = __int_as_float(p5[2]);
        q3.x = __int_as_float(p6[0]); q3.y = __int_as_float(p6[2]);
        q3.z = __int_as_float(p7[0]); q3.w = __int_as_float(p7[2]);
        *(float4*)(d + 0) = q0;
        *(float4*)(d + 4) = q1;
        *(float4*)(d + 8) = q2;
        *(float4*)(d + 12) = q3;
      } else {
#pragma unroll
        for (int q = 0; q < 16; ++q) d[q] = 0.f;
      }
    }
    __syncthreads();   // A1: h(t) staged

    // ---- x-half GEMM: k in [ks*16, ks*16+16) from in_s x-half ----
    float acc[4][BPB];
#pragma unroll
    for (int jj = 0; jj < 4; ++jj)
#pragma unroll
      for (int bi = 0; bi < BPB; ++bi) acc[jj][bi] = 0.f;
    {
      const int fb = fpad(ks * KHALF);
#pragma unroll
      for (int bi = 0; bi < BPB; ++bi) {
        const float* inp = &in_s[bi][fb];
#pragma unroll
        for (int kk = 0; kk < KHALF; ++kk) {
          float x = inp[kk];
          acc[0][bi] = fmaf(w[0][kk], x, acc[0][bi]);
          acc[1][bi] = fmaf(w[1][kk], x, acc[1][bi]);
          acc[2][bi] = fmaf(w[2][kk], x, acc[2][bi]);
          acc[3][bi] = fmaf(w[3][kk], x, acc[3][bi]);
        }
      }
    }

    // ---- h-half GEMM: k in [512 + ks*16, +16) ----
    {
      const int fb = fpad(NH + ks * KHALF);
#pragma unroll
      for (int bi = 0; bi < BPB; ++bi) {
        const float* inp = &in_s[bi][fb];
#pragma unroll
        for (int kk = 0; kk < KHALF; ++kk) {
          float x = inp[kk];
          acc[0][bi] = fmaf(w[0][KHALF + kk], x, acc[0][bi]);
          acc[1][bi] = fmaf(w[1][KHALF + kk], x, acc[1][bi]);
          acc[2][bi] = fmaf(w[2][KHALF + kk], x, acc[2][bi]);
          acc[3][bi] = fmaf(w[3][KHALF + kk], x, acc[3][bi]);
        }
      }
    }
#pragma unroll
    for (int jj = 0; jj < 4; ++jj) {
      int r = jg * 4 + jj;
#pragma unroll
      for (int bi = 0; bi < BPB; ++bi)
        p_s[ks][r * BPB + bi] = acc[jj][bi];
    }
    __syncthreads();   // B: p_s complete; in_s x-half dead

    // ---- prefetch x(t+1) into in_s x-half (cached; off critical path) ----
    if (more) {
      int e = ev[(t + 1) * NB + b0 + sb2];
      float4 v0 = *(const float4*)(path + (size_t)e * NH + off4);
      *(float4*)&in_s[sb2][fpad(off4)] = v0;
    }

    // ---- reduce 32 k-slices + bias ----
    if (tid < NJ * BPB) {
      float s = 0.f;
#pragma unroll
      for (int k2 = 0; k2 < 32; ++k2) s += p_s[k2][tid];
      int r = tid >> 2;
      s += gate_b[(r >> 4) * NH + u0 + (r & 15)];
      zred[tid] = s;
    }
    __syncthreads();   // C: zred complete

    // ---- gates + state update + tagged handoff + EARLY signal ----
    if (tid < BPB * UPB) {
      int bi = tid >> 4, uu = tid & 15;
      float zi = zred[(uu) * BPB + bi];
      float zf = zred[(UPB + uu) * BPB + bi];
      float zg = zred[(2 * UPB + uu) * BPB + bi];
      float zo = zred[(3 * UPB + uu) * BPB + bi];
      float ig = 1.f / (1.f + expf(-zi));
      float fg = 1.f / (1.f + expf(-zf));
      float gg = tanhf(zg);
      float ogv = 1.f / (1.f + expf(-zo));
      float cv = fmaf(fg, c_s[bi][uu], ig * gg);
      float hvv = ogv * tanhf(cv);
      c_s[bi][uu] = cv;
      int b = b0 + bi, u = u0 + uu;
      if (more) {
        int* pdst = hpair + (((size_t)((t + 1) & 1) * NB + b) * NH + u) * 2;
        v2i pr;
        pr[0] = __float_as_int(hvv);
        pr[1] = t + 1;
        asm volatile("global_store_dwordx2 %0, %1, off sc0 sc1"
                     :: "v"(pdst), "v"(pr) : "memory");
      }
      // EARLY signal: no drain -- the hint may lead the data; tags protect.
      if (more && tid == 0) {
        int nv = t + 1;
        asm volatile("global_store_dword %0, %1, off sc0 sc1"
                     :: "v"(myprog), "v"(nv) : "memory");
      }
      // output stores off the critical path (after the handoff)
      size_t o0 = ((size_t)t * NB + b) * NH + u;
      out[o0] = hvv;
      out[plane + o0] = cv;
      out[2 * plane + o0] = ogv;
    }
    // no end-of-step barrier: next iteration's poll + A0 covers it
  }
}

extern "C" void kernel_launch(void* const* d_in, const int* in_sizes, int n_in,
                              void* d_out, int out_size, void* d_ws, size_t ws_size,
                              hipStream_t stream) {
  const int* ev = (const int*)d_in[0];
  const int* parents = (const int*)d_in[1];
  const float* weight = (const float*)d_in[2];
  const float* emb = (const float*)d_in[3];
  const float* gate_w = (const float*)d_in[4];
  const float* gate_b = (const float*)d_in[5];
  float* out = (float*)d_out;

  char* ws = (char*)d_ws;
  float* path = (float*)ws;
  size_t path_bytes = (size_t)NV * NH * sizeof(float);
  int* hpair = (int*)(ws + path_bytes);
  size_t hpair_bytes = (size_t)2 * NB * NH * 2 * sizeof(int);
  int* prog = (int*)(ws + path_bytes + hpair_bytes);

  init_kernel<<<(2 * NB * NH * 2 + 255) / 256, 256, 0, stream>>>(hpair, prog);
  path_kernel<<<NV, 256, 0, stream>>>(parents, weight, emb, path);
  lstm_kernel<<<NGRP * BPG, NTH, 0, stream>>>(ev, path, gate_w, gate_b, hpair,
                                              prog, out);
}

// Round 24
// 4370.731 us; speedup vs baseline: 4.0641x; 3.0214x over previous
//
#include <hip/hip_runtime.h>
#include <math.h>

// Problem constants (fixed by the reference)
#define NV 20000
#define NH 512
#define NT 1024
#define NB 32
#define MAXD 64

// LSTM persistent-kernel geometry (R13-proven chassis)
#define NGRP 8      // groups (independent batch-row sets); sync domain = 1 group
#define BPG 32      // blocks per group
#define BPB 4       // batch rows per group  (NB / NGRP)
#define UPB 16      // hidden units per block (NH / BPG)
#define NJ 64       // gate rows per block = 4*UPB
#define KTOT 1024   // 2*NH
#define NTH 512
#define KHALF 16    // k floats per thread per half (x + h = 32 floats = 16 pairs)
#define PPAD 576    // padded packed row: 512 pairs + 4 per 32

typedef int v4i __attribute__((ext_vector_type(4)));
typedef __fp16 v2h __attribute__((ext_vector_type(2)));

// packed-pair pad: +4 u32 per 32 -> preserves 16B alignment, <=2-way LDS
// bank aliasing on the GEMM's b128 reads (2-way is free, m136)
__device__ __forceinline__ int fpadp(int p) { return p + ((p >> 5) << 2); }
// f32 pad (x staging source layout in path is untouched)
__device__ __forceinline__ int fpad(int k) { return k + (k >> 5); }

// ws layout: [ path: NV*NH f32 | hbuf: 2*NB*NH f32 | prog: 256 ints ] ~= 41.1 MB

__global__ void init_kernel(float* __restrict__ hbuf, int* __restrict__ prog) {
  int i = blockIdx.x * blockDim.x + threadIdx.x;
  if (i < 2 * NB * NH)
    __hip_atomic_store(&hbuf[i], 0.f, __ATOMIC_RELAXED, __HIP_MEMORY_SCOPE_SYSTEM);
  if (i < 256)
    __hip_atomic_store(&prog[i], 0, __ATOMIC_RELAXED, __HIP_MEMORY_SCOPE_SYSTEM);
}

// One block per node: all 256 threads walk the same parent chain (uniform),
// each thread accumulates 2 of the 512 embedding columns (coalesced).
__global__ __launch_bounds__(256)
void path_kernel(const int* __restrict__ parents,
                 const float* __restrict__ weight,
                 const float* __restrict__ emb,
                 float* __restrict__ path) {
  int v = blockIdx.x;
  int h = threadIdx.x;
  float acc0 = 0.f, acc1 = 0.f;
  float w = 1.f;
  int cur = v;
#pragma unroll 1
  for (int d = 0; d < MAXD; ++d) {
    if (cur < 0) break;
    const float* row = emb + (size_t)cur * NH;
    acc0 = fmaf(w, row[h], acc0);
    acc1 = fmaf(w, row[h + 256], acc1);
    w *= weight[cur];
    cur = parents[cur];
  }
  path[(size_t)v * NH + h] = acc0;
  path[(size_t)v * NH + h + 256] = acc1;
}

// Persistent LSTM, R24 = R23 with the v2h typedef fixed (__fp16 vector, the
// return type of __builtin_amdgcn_cvt_pkrtz). Packed-f16 v_dot2 GEMM;
// exchange machinery byte-identical to R13.
// Rationale: 7 protocol nulls around a 12.2us step; VGPR_Count pinned at 128
// in every round while f32 demand is ~165 -- the allocator covers the
// deficit invisibly, and ~10-20 MB/step of FETCH has never been accounted
// for by protocol traffic (R17: 8x poll-rate cut, zero FETCH change). This
// round halves both register demand (w: 128 f32 -> 64 packed half2 VGPRs;
// total ~105 < 128) and VALU work (fdot2 = 2 MACs/instr, fp32 accum).
// f16 input error ~5e-4 rel, z error ~1e-3 << 1.125e-2 threshold.
__global__ __launch_bounds__(NTH, 1)
void lstm_kernel(const int* __restrict__ ev,
                 const float* __restrict__ path,
                 const float* __restrict__ gate_w,
                 const float* __restrict__ gate_b,
                 float* __restrict__ hbuf,   // [2][NB][NH]
                 int* __restrict__ prog,     // [NGRP][BPG] per-producer step ctr
                 float* __restrict__ out) {  // [3][NT][NB][NH]
  __shared__ unsigned int in2[BPB][PPAD];    // packed [x(t) | h(t)] half2
  __shared__ float p_s[32][NJ * BPB + 1];    // stride 257 -> conflict-free
  __shared__ float zred[NJ * BPB];
  __shared__ float c_s[BPB][UPB];

  const int bid = blockIdx.x;
  const int grp = bid >> 5;   // group = consecutive 32-block range
  const int blk = bid & 31;
  const int b0 = grp * BPB;
  const int u0 = blk * UPB;
  const int tid = threadIdx.x;
  const int jg = tid >> 5;   // 0..15: which 4-row group of gate rows
  const int ks = tid & 31;   // 0..31: which k-slice (16 x-floats + 16 h-floats)

  // gate_w slice, packed: w2[jj][0..7] = x-half pairs, [8..15] = h-half pairs
  v2h w2[4][2 * (KHALF / 2)];
#pragma unroll
  for (int jj = 0; jj < 4; ++jj) {
    int r = jg * 4 + jj;                        // 0..63: gate*16 + uu
    int j = (r >> 4) * NH + u0 + (r & 15);      // global gate row
    const float* wx = gate_w + (size_t)j * KTOT + ks * KHALF;
    const float* wh = gate_w + (size_t)j * KTOT + NH + ks * KHALF;
#pragma unroll
    for (int kk = 0; kk < KHALF / 2; ++kk) {
      w2[jj][kk] = __builtin_amdgcn_cvt_pkrtz(wx[2 * kk], wx[2 * kk + 1]);
      w2[jj][8 + kk] = __builtin_amdgcn_cvt_pkrtz(wh[2 * kk], wh[2 * kk + 1]);
    }
  }

  if (tid < BPB * UPB) c_s[tid >> 4][tid & 15] = 0.f;

  // staging maps
  const int sb2 = tid >> 7;          // x-prefetch: row 0..3
  const int off4 = (tid & 127) * 4;  // x-prefetch: 4-float chunk
  const int hrow = tid >> 5;         // h-stage (tid<128): row 0..3
  const int hc16 = (tid & 31) * 16;  // h-stage: 16-float (64B) chunk
  const size_t plane = (size_t)NT * NB * NH;
  int* myprog = prog + grp * BPG + blk;
  const int* pollp4 = prog + grp * BPG + (tid & 7) * 4;

  // pre-stage x(0): load f32, pack to half2 pairs
  {
    int e = ev[0 * NB + b0 + sb2];
    float4 v0 = *(const float4*)(path + (size_t)e * NH + off4);
    v2h a = __builtin_amdgcn_cvt_pkrtz(v0.x, v0.y);
    v2h b = __builtin_amdgcn_cvt_pkrtz(v0.z, v0.w);
    int p0 = (tid & 127) * 2;
    uint2 pr;
    pr.x = __builtin_bit_cast(unsigned int, a);
    pr.y = __builtin_bit_cast(unsigned int, b);
    *(uint2*)&in2[sb2][fpadp(p0)] = pr;
  }

#pragma unroll 1
  for (int t = 0; t < NT; ++t) {
    const bool more = (t + 1 < NT);

    // ---- wait for group's h(t) producers: 8 lanes x dwordx4 ----
    if (t > 0 && tid < 8) {
      v4i pv;
      for (;;) {
        asm volatile("global_load_dwordx4 %0, %1, off sc0 sc1\n\ts_waitcnt vmcnt(0)"
                     : "=v"(pv) : "v"(pollp4) : "memory");
        bool ok = (pv[0] >= t) && (pv[1] >= t) && (pv[2] >= t) && (pv[3] >= t);
        if ((__ballot(ok) & 0xFFull) == 0xFFull) break;
        __builtin_amdgcn_s_sleep(1);
      }
    }
    __syncthreads();   // A0: poll passed; prev step's LDS reads all complete

    // ---- stage h(t): 128 lanes x one 64B line (4 fused dwordx4) + pack ----
    if (tid < 128) {
      unsigned int* d = &in2[hrow][fpadp(NH / 2 + (tid & 31) * 8)];
      if (t > 0) {
        const float* hsrc =
            hbuf + ((size_t)(t & 1) * NB + (b0 + hrow)) * NH + hc16;
        float4 ha, hb, hc, hd;
        asm volatile(
            "global_load_dwordx4 %0, %4, off sc0 sc1\n\t"
            "global_load_dwordx4 %1, %4, off offset:16 sc0 sc1\n\t"
            "global_load_dwordx4 %2, %4, off offset:32 sc0 sc1\n\t"
            "global_load_dwordx4 %3, %4, off offset:48 sc0 sc1\n\t"
            "s_waitcnt vmcnt(0)"
            : "=&v"(ha), "=&v"(hb), "=&v"(hc), "=&v"(hd)
            : "v"(hsrc)
            : "memory");
        uint4 q0, q1;
        q0.x = __builtin_bit_cast(unsigned int, __builtin_amdgcn_cvt_pkrtz(ha.x, ha.y));
        q0.y = __builtin_bit_cast(unsigned int, __builtin_amdgcn_cvt_pkrtz(ha.z, ha.w));
        q0.z = __builtin_bit_cast(unsigned int, __builtin_amdgcn_cvt_pkrtz(hb.x, hb.y));
        q0.w = __builtin_bit_cast(unsigned int, __builtin_amdgcn_cvt_pkrtz(hb.z, hb.w));
        q1.x = __builtin_bit_cast(unsigned int, __builtin_amdgcn_cvt_pkrtz(hc.x, hc.y));
        q1.y = __builtin_bit_cast(unsigned int, __builtin_amdgcn_cvt_pkrtz(hc.z, hc.w));
        q1.z = __builtin_bit_cast(unsigned int, __builtin_amdgcn_cvt_pkrtz(hd.x, hd.y));
        q1.w = __builtin_bit_cast(unsigned int, __builtin_amdgcn_cvt_pkrtz(hd.z, hd.w));
        *(uint4*)(d + 0) = q0;   // fpadp keeps 16B alignment (pad = 4 per 32)
        *(uint4*)(d + 4) = q1;
      } else {
        uint4 z; z.x = 0u; z.y = 0u; z.z = 0u; z.w = 0u;
        *(uint4*)(d + 0) = z;
        *(uint4*)(d + 4) = z;
      }
    }
    __syncthreads();   // A1: h(t) staged

    // ---- GEMM via fdot2: 4 rows x 4 batch x 16 pairs per thread ----
    float acc[4][BPB];
#pragma unroll
    for (int jj = 0; jj < 4; ++jj)
#pragma unroll
      for (int bi = 0; bi < BPB; ++bi) acc[jj][bi] = 0.f;
    {
      const int fbx = fpadp(ks * (KHALF / 2));            // x-half pairs
      const int fbh = fpadp(NH / 2 + ks * (KHALF / 2));   // h-half pairs
#pragma unroll
      for (int bi = 0; bi < BPB; ++bi) {
        const unsigned int* px = &in2[bi][fbx];
        const unsigned int* ph = &in2[bi][fbh];
#pragma unroll
        for (int kk = 0; kk < KHALF / 2; ++kk) {
          v2h x = __builtin_bit_cast(v2h, px[kk]);
          acc[0][bi] = __builtin_amdgcn_fdot2(w2[0][kk], x, acc[0][bi], false);
          acc[1][bi] = __builtin_amdgcn_fdot2(w2[1][kk], x, acc[1][bi], false);
          acc[2][bi] = __builtin_amdgcn_fdot2(w2[2][kk], x, acc[2][bi], false);
          acc[3][bi] = __builtin_amdgcn_fdot2(w2[3][kk], x, acc[3][bi], false);
        }
#pragma unroll
        for (int kk = 0; kk < KHALF / 2; ++kk) {
          v2h x = __builtin_bit_cast(v2h, ph[kk]);
          acc[0][bi] = __builtin_amdgcn_fdot2(w2[0][8 + kk], x, acc[0][bi], false);
          acc[1][bi] = __builtin_amdgcn_fdot2(w2[1][8 + kk], x, acc[1][bi], false);
          acc[2][bi] = __builtin_amdgcn_fdot2(w2[2][8 + kk], x, acc[2][bi], false);
          acc[3][bi] = __builtin_amdgcn_fdot2(w2[3][8 + kk], x, acc[3][bi], false);
        }
      }
    }
#pragma unroll
    for (int jj = 0; jj < 4; ++jj) {
      int r = jg * 4 + jj;
#pragma unroll
      for (int bi = 0; bi < BPB; ++bi)
        p_s[ks][r * BPB + bi] = acc[jj][bi];
    }
    __syncthreads();   // B: p_s complete; in2 x-half dead

    // ---- prefetch x(t+1) into in2 x-half (cached; off critical path) ----
    if (more) {
      int e = ev[(t + 1) * NB + b0 + sb2];
      float4 v0 = *(const float4*)(path + (size_t)e * NH + off4);
      v2h a = __builtin_amdgcn_cvt_pkrtz(v0.x, v0.y);
      v2h b = __builtin_amdgcn_cvt_pkrtz(v0.z, v0.w);
      int p0 = (tid & 127) * 2;
      uint2 pr;
      pr.x = __builtin_bit_cast(unsigned int, a);
      pr.y = __builtin_bit_cast(unsigned int, b);
      *(uint2*)&in2[sb2][fpadp(p0)] = pr;
    }

    // ---- reduce 32 k-slices + bias ----
    if (tid < NJ * BPB) {
      float s = 0.f;
#pragma unroll
      for (int k2 = 0; k2 < 32; ++k2) s += p_s[k2][tid];
      int r = tid >> 2;
      s += gate_b[(r >> 4) * NH + u0 + (r & 15)];
      zred[tid] = s;
    }
    __syncthreads();   // C: zred complete

    // ---- gates + state update + handoff (wave 0 only) ----
    if (tid < BPB * UPB) {
      int bi = tid >> 4, uu = tid & 15;
      float zi = zred[(uu) * BPB + bi];
      float zf = zred[(UPB + uu) * BPB + bi];
      float zg = zred[(2 * UPB + uu) * BPB + bi];
      float zo = zred[(3 * UPB + uu) * BPB + bi];
      float ig = 1.f / (1.f + expf(-zi));
      float fg = 1.f / (1.f + expf(-zf));
      float gg = tanhf(zg);
      float ogv = 1.f / (1.f + expf(-zo));
      float cv = fmaf(fg, c_s[bi][uu], ig * gg);
      float hvv = ogv * tanhf(cv);
      c_s[bi][uu] = cv;
      int b = b0 + bi, u = u0 + uu;
      if (more) {
        float* hdst = hbuf + ((size_t)((t + 1) & 1) * NB + b) * NH + u;
        __hip_atomic_store(hdst, hvv, __ATOMIC_RELAXED, __HIP_MEMORY_SCOPE_SYSTEM);
      }
      // announce: wave-level drain of the h stores, then per-producer word
      if (more && tid == 0) {
        asm volatile("s_waitcnt vmcnt(0)" ::: "memory");
        int nv = t + 1;
        asm volatile("global_store_dword %0, %1, off sc0 sc1"
                     :: "v"(myprog), "v"(nv) : "memory");
      }
      // output stores off the critical path (after the signal)
      size_t o0 = ((size_t)t * NB + b) * NH + u;
      out[o0] = hvv;
      out[plane + o0] = cv;
      out[2 * plane + o0] = ogv;
    }
    // no end-of-step barrier: next iteration's poll + A0 covers it
  }
}

extern "C" void kernel_launch(void* const* d_in, const int* in_sizes, int n_in,
                              void* d_out, int out_size, void* d_ws, size_t ws_size,
                              hipStream_t stream) {
  const int* ev = (const int*)d_in[0];
  const int* parents = (const int*)d_in[1];
  const float* weight = (const float*)d_in[2];
  const float* emb = (const float*)d_in[3];
  const float* gate_w = (const float*)d_in[4];
  const float* gate_b = (const float*)d_in[5];
  float* out = (float*)d_out;

  char* ws = (char*)d_ws;
  float* path = (float*)ws;
  size_t path_bytes = (size_t)NV * NH * sizeof(float);
  float* hbuf = (float*)(ws + path_bytes);
  int* prog = (int*)(ws + path_bytes + (size_t)2 * NB * NH * sizeof(float));

  init_kernel<<<(2 * NB * NH + 255) / 256, 256, 0, stream>>>(hbuf, prog);
  path_kernel<<<NV, 256, 0, stream>>>(parents, weight, emb, path);
  lstm_kernel<<<NGRP * BPG, NTH, 0, stream>>>(ev, path, gate_w, gate_b, hbuf, prog, out);
}